// Round 13
// baseline (1469.446 us; speedup 1.0000x reference)
//
#include <hip/hip_runtime.h>
#include <hip/hip_bf16.h>
#include <hip/hip_fp16.h>

// 2-layer GCN (PyG GCNConv) on MI355X. N=100000, E=1.6M, IN=128, HID=OUT=64.
//
// Algebra: y = (x@W) * dinv[row]; agg[d] = y[d] + sum_{e:(s->d)} y[s];
//          out[d] = agg[d]*dinv[d] + b  (self-loop folded into agg init).
//
// Aggregation (R13): chunk-synchronized LDS-tile accumulation.
//   fill: entry (src<<6)|(dst&63) -> segment (dst-bucket, src>>14, blockIdx&7).
//   agg:  1 block per 64-row dst bucket, 8 waves; wave w sweeps src-chunks
//         0..7 (segment slot w), 16-deep predicated gather ILP, ds_add_f32
//         into f32 tile. All blocks sweep chunks in the same order -> the
//         instantaneous gather working set is ~1.6MB (fits per-XCD L2) ->
//         gathers are L2 HITS (tests the miss-service-bound hypothesis).
// y1/y2 fp16 storage (accumulation f32). gemm2 fused on the LDS tile.
//
// Workspace: cnt @0 (400KB)  dinv @0.5MB (400KB)  bcur @1MB (6.4MB)
//            ents @8MB (25.6MB)  y1 @34MB (12.8MB)  y2 @47MB (12.8MB) = 60MB

#define IN_DIM 128
#define HID 64
#define CAPS 64      // per (bucket,chunk,xcd) capacity; lambda~21 -> +9 sigma
#define CURPAD 16
#define NCHUNK 8     // src>>14 in 0..6 (+1 spare slot)

__global__ __launch_bounds__(256) void fill_kernel(
    const int* __restrict__ src, const int* __restrict__ dst,
    int* __restrict__ cnt, int* __restrict__ bcur, int* __restrict__ ents, int E) {
  int e = blockIdx.x * 256 + threadIdx.x;
  if (e >= E) return;
  int s = src[e], d = dst[e];
  atomicAdd(&cnt[d], 1);  // degree for dinv
  int seg = ((d >> 6) << 6) | ((((unsigned)s >> 14) & 7) << 3) | (blockIdx.x & 7);
  int pos = atomicAdd(&bcur[seg * CURPAD], 1);
  if (pos < CAPS) ents[(size_t)seg * CAPS + pos] = (s << 6) | (d & 63);
}

__global__ void dinv_kernel(const int* __restrict__ cnt, float* __restrict__ dinv, int N) {
  int i = blockIdx.x * blockDim.x + threadIdx.x;
  if (i < N) dinv[i] = rsqrtf((float)(cnt[i] + 1));  // +1 self loop
}

// y1 = fp16((x @ W1) * dinv[row]). Register-tiled 64x64/block, 4x4 acc/thread.
__global__ __launch_bounds__(256) void gemm1_kernel(
    const float* __restrict__ x, const float* __restrict__ W1,
    const float* __restrict__ dinv, __half* __restrict__ y1, int N) {
  __shared__ float Xs[IN_DIM][68];
  __shared__ float Ws[IN_DIM * HID];

  for (int i = threadIdx.x; i < IN_DIM * HID / 4; i += 256)
    ((float4*)Ws)[i] = ((const float4*)W1)[i];

  int r0 = blockIdx.x * 64;
  {
    int row = threadIdx.x >> 2;
    int kc = (threadIdx.x & 3) * 32;
    int gr = r0 + row;
    const float* xp = x + (size_t)(gr < N ? gr : N - 1) * IN_DIM + kc;
#pragma unroll
    for (int i = 0; i < 8; ++i) {
      float4 v = *(const float4*)(xp + i * 4);
      int k = kc + i * 4;
      Xs[k + 0][row] = v.x;
      Xs[k + 1][row] = v.y;
      Xs[k + 2][row] = v.z;
      Xs[k + 3][row] = v.w;
    }
  }
  __syncthreads();

  int tr = (threadIdx.x & 15) * 4;
  int tc = (threadIdx.x >> 4) * 4;
  float acc[4][4];
#pragma unroll
  for (int i = 0; i < 4; ++i)
#pragma unroll
    for (int j = 0; j < 4; ++j) acc[i][j] = 0.f;

#pragma unroll 8
  for (int k = 0; k < IN_DIM; ++k) {
    float4 a = *(const float4*)&Xs[k][tr];
    float4 bb = *(const float4*)&Ws[k * HID + tc];
    acc[0][0] = fmaf(a.x, bb.x, acc[0][0]); acc[0][1] = fmaf(a.x, bb.y, acc[0][1]);
    acc[0][2] = fmaf(a.x, bb.z, acc[0][2]); acc[0][3] = fmaf(a.x, bb.w, acc[0][3]);
    acc[1][0] = fmaf(a.y, bb.x, acc[1][0]); acc[1][1] = fmaf(a.y, bb.y, acc[1][1]);
    acc[1][2] = fmaf(a.y, bb.z, acc[1][2]); acc[1][3] = fmaf(a.y, bb.w, acc[1][3]);
    acc[2][0] = fmaf(a.z, bb.x, acc[2][0]); acc[2][1] = fmaf(a.z, bb.y, acc[2][1]);
    acc[2][2] = fmaf(a.z, bb.z, acc[2][2]); acc[2][3] = fmaf(a.z, bb.w, acc[2][3]);
    acc[3][0] = fmaf(a.w, bb.x, acc[3][0]); acc[3][1] = fmaf(a.w, bb.y, acc[3][1]);
    acc[3][2] = fmaf(a.w, bb.z, acc[3][2]); acc[3][3] = fmaf(a.w, bb.w, acc[3][3]);
  }

#pragma unroll
  for (int i = 0; i < 4; ++i) {
    int r = r0 + tr + i;
    if (r < N) {
      float di = dinv[r];
      ushort4 w;
      w.x = __half_as_ushort(__float2half(acc[i][0] * di));
      w.y = __half_as_ushort(__float2half(acc[i][1] * di));
      w.z = __half_as_ushort(__float2half(acc[i][2] * di));
      w.w = __half_as_ushort(__float2half(acc[i][3] * di));
      *(ushort4*)(y1 + ((size_t)r << 6) + tc) = w;
    }
  }
}

// 16-deep predicated gather+ds_add step (load always issued, add predicated).
#define TSTEP(U) {                                                      \
    int e_ = __shfl(ent, i + U);                                        \
    unsigned s_ = (U < rem) ? ((unsigned)e_ >> 6) : 0u;                 \
    float v_ = __half2float(y[(s_ << 6) | lane]);                       \
    if (U < rem) unsafeAtomicAdd(&tile[e_ & 63][lane], v_);             \
  }

// Accumulate all bucket entries into tile; wave w sweeps chunks, slot w.
__device__ __forceinline__ void tile_accumulate(
    float (*tile)[HID], const __half* __restrict__ y,
    const int* __restrict__ ents, const int* __restrict__ bcur,
    int b, int wave, unsigned lane) {
  for (int c = 0; c < NCHUNK; ++c) {
    int seg = (b << 6) | (c << 3) | wave;
    int n = bcur[seg * CURPAD];
    n = n < CAPS ? n : CAPS;
    if (n == 0) continue;
    const int* ep = ents + (size_t)seg * CAPS;
    int ent = ((int)lane < n) ? ep[lane] : 0;
    for (int i = 0; i < n; i += 16) {
      int rem = n - i;
      TSTEP(0)  TSTEP(1)  TSTEP(2)  TSTEP(3)
      TSTEP(4)  TSTEP(5)  TSTEP(6)  TSTEP(7)
      TSTEP(8)  TSTEP(9)  TSTEP(10) TSTEP(11)
      TSTEP(12) TSTEP(13) TSTEP(14) TSTEP(15)
    }
  }
}

// Layer 1: tile = self + neighbors; h = relu(tile*dinv+b1); y2 = fp16((h@W2)*dinv).
__global__ __launch_bounds__(512) void agg1_tile_kernel(
    const __half* __restrict__ y1, const int* __restrict__ ents,
    const int* __restrict__ bcur, const float* __restrict__ dinv,
    const float* __restrict__ b1, const float* __restrict__ W2,
    __half* __restrict__ y2, int N) {
  __shared__ float tile[64][HID];   // 16KB; bank = lane%32 -> 2-way (free)
  __shared__ float W2s[HID * HID];  // 16KB
  int b = blockIdx.x, r0 = b << 6;
  int tid = threadIdx.x, wave = tid >> 6;
  unsigned lane = tid & 63;

  for (int i = tid; i < HID * HID / 4; i += 512)
    ((float4*)W2s)[i] = ((const float4*)W2)[i];

#pragma unroll
  for (int j = 0; j < 8; ++j) {  // init with self-loop rows
    int i = (wave << 3) + j;
    int r = r0 + i;
    tile[i][lane] = (r < N) ? __half2float(y1[((unsigned)r << 6) | lane]) : 0.f;
  }
  __syncthreads();

  tile_accumulate(tile, y1, ents, bcur, b, wave, lane);
  __syncthreads();

  float bv = b1[lane];
#pragma unroll
  for (int j = 0; j < 8; ++j) {  // relu epilogue in place
    int i = (wave << 3) + j;
    int r = r0 + i;
    float di = (r < N) ? dinv[r] : 0.f;
    tile[i][lane] = fmaxf(fmaf(tile[i][lane], di, bv), 0.f);
  }
  __syncthreads();

#pragma unroll 2
  for (int j = 0; j < 8; ++j) {  // gemm2 from tile
    int i = (wave << 3) + j;
    int r = r0 + i;
    if (r >= N) continue;
    float c0 = 0.f, c1 = 0.f, c2 = 0.f, c3 = 0.f;
#pragma unroll
    for (int k = 0; k < HID; k += 4) {
      float4 hv = *(const float4*)&tile[i][k];
      c0 = fmaf(hv.x, W2s[(k + 0) * HID + lane], c0);
      c1 = fmaf(hv.y, W2s[(k + 1) * HID + lane], c1);
      c2 = fmaf(hv.z, W2s[(k + 2) * HID + lane], c2);
      c3 = fmaf(hv.w, W2s[(k + 3) * HID + lane], c3);
    }
    y2[((unsigned)r << 6) | lane] = __float2half(((c0 + c1) + (c2 + c3)) * dinv[r]);
  }
}

// Layer 2: tile = self + neighbors; out = tile*dinv + b2 (f32).
__global__ __launch_bounds__(512) void agg2_tile_kernel(
    const __half* __restrict__ y2, const int* __restrict__ ents,
    const int* __restrict__ bcur, const float* __restrict__ dinv,
    const float* __restrict__ b2, float* __restrict__ out, int N) {
  __shared__ float tile[64][HID];
  int b = blockIdx.x, r0 = b << 6;
  int tid = threadIdx.x, wave = tid >> 6;
  unsigned lane = tid & 63;

#pragma unroll
  for (int j = 0; j < 8; ++j) {
    int i = (wave << 3) + j;
    int r = r0 + i;
    tile[i][lane] = (r < N) ? __half2float(y2[((unsigned)r << 6) | lane]) : 0.f;
  }
  __syncthreads();

  tile_accumulate(tile, y2, ents, bcur, b, wave, lane);
  __syncthreads();

  float bv = b2[lane];
#pragma unroll
  for (int j = 0; j < 8; ++j) {
    int i = (wave << 3) + j;
    int r = r0 + i;
    if (r < N)
      out[((unsigned)r << 6) | lane] = fmaf(tile[i][lane], dinv[r], bv);
  }
}

extern "C" void kernel_launch(void* const* d_in, const int* in_sizes, int n_in,
                              void* d_out, int out_size, void* d_ws, size_t ws_size,
                              hipStream_t stream) {
  const float* x   = (const float*)d_in[0];
  const int* edges = (const int*)d_in[1];
  const float* W1  = (const float*)d_in[2];
  const float* b1  = (const float*)d_in[3];
  const float* W2  = (const float*)d_in[4];
  const float* b2  = (const float*)d_in[5];
  float* out = (float*)d_out;

  const int N = in_sizes[0] / IN_DIM;   // 100000
  const int E = in_sizes[1] / 2;        // 1600000
  const int* src = edges;
  const int* dst = edges + E;
  const int NBUCK = (N + 63) / 64;      // 1563

  char* wsb = (char*)d_ws;
  int*    cnt  = (int*)(wsb + 0);                          // 400KB
  float*  dinv = (float*)(wsb + (size_t)512 * 1024);       // 400KB
  int*    bcur = (int*)(wsb + (size_t)1024 * 1024);        // NBUCK*64*16*4 = 6.4MB
  int*    ents = (int*)(wsb + (size_t)8 * 1024 * 1024);    // NBUCK*64*64*4 = 25.6MB
  __half* y1   = (__half*)(wsb + (size_t)34 * 1024 * 1024); // 12.8MB
  __half* y2   = (__half*)(wsb + (size_t)47 * 1024 * 1024); // 12.8MB, ends ~60MB

  const int blk = 256;
  int gE = (E + blk - 1) / blk;
  int gN = (N + blk - 1) / blk;
  int gG = (N + 63) / 64;

  hipMemsetAsync(cnt, 0, (size_t)N * 4, stream);
  hipMemsetAsync(bcur, 0, (size_t)NBUCK * 64 * CURPAD * 4, stream);
  fill_kernel<<<gE, blk, 0, stream>>>(src, dst, cnt, bcur, ents, E);
  dinv_kernel<<<gN, blk, 0, stream>>>(cnt, dinv, N);

  gemm1_kernel<<<gG, blk, 0, stream>>>(x, W1, dinv, y1, N);
  agg1_tile_kernel<<<NBUCK, 512, 0, stream>>>(y1, ents, bcur, dinv, b1, W2, y2, N);
  agg2_tile_kernel<<<NBUCK, 512, 0, stream>>>(y2, ents, bcur, dinv, b2, out, N);
}

// Round 14
// 308.516 us; speedup vs baseline: 4.7630x; 4.7630x over previous
//
#include <hip/hip_runtime.h>
#include <hip/hip_bf16.h>
#include <hip/hip_fp16.h>

// 2-layer GCN (PyG GCNConv) on MI355X. N=100000, E=1.6M, IN=128, HID=OUT=64.
//
// Algebra: y = (x@W) * dinv[row]; agg[d] = y[d] + sum_{e:(s->d)} y[s];
//          out[d] = agg[d]*dinv[d] + b  (self-loop folded into agg init).
//
// CSR via bucketed fill (XCD-affine sub-segments, packed (src<<6)|(dst&63))
// + per-bucket LDS counting sort (in-place, no global scan).
// Aggregation: one wave per row, 16-deep gather ILP (R10 best structure),
// NON-TEMPORAL gather loads: gathered rows have no intra-CU reuse (reuse is
// cross-CU via L2/L3), so L1 retention only burns miss slots. Tests the
// L1-miss-service-floor hypothesis.
// y1/y2 stored FP16 (storage only; accumulation f32).
//
// Workspace (no overlaps; peak 42.8MB):
//   dinv @0 (400KB)  start_ @0.5MB  end_ @1.0MB  bcur @1.5MB (800KB)
//   ents=csr @3MB (12.8MB)  y1 @16MB (12.8MB)  y2 @30MB (12.8MB)

#define IN_DIM 128
#define HID 64
#define SUB 8
#define CAPS 256
#define CURPAD 16
#define BENT (SUB * CAPS)

__global__ __launch_bounds__(256) void fill_kernel(
    const int* __restrict__ src, const int* __restrict__ dst,
    int* __restrict__ bcur, int* __restrict__ ents, int E) {
  int e = blockIdx.x * 256 + threadIdx.x;
  if (e >= E) return;
  int s = src[e], d = dst[e];
  int seg = (d >> 6) * SUB + (blockIdx.x & 7);
  int pos = atomicAdd(&bcur[seg * CURPAD], 1);
  if (pos < CAPS) ents[(size_t)seg * CAPS + pos] = (s << 6) | (d & 63);
}

__global__ __launch_bounds__(256) void sort_kernel(
    const int* __restrict__ ents, const int* __restrict__ bcur,
    int* __restrict__ csr, int* __restrict__ start_, int* __restrict__ end_,
    float* __restrict__ dinv, int N) {
  __shared__ int stage[BENT];
  __shared__ int sorted[BENT];
  __shared__ int scnt[SUB], soff[SUB + 1];
  __shared__ int hist[64], cur[64];
  int b = blockIdx.x, tid = threadIdx.x;
  int base = b * BENT;

  if (tid < SUB) {
    int c = bcur[(b * SUB + tid) * CURPAD];
    scnt[tid] = c < CAPS ? c : CAPS;
  }
  if (tid < 64) hist[tid] = 0;
  __syncthreads();
  if (tid == 0) {
    int a = 0;
#pragma unroll
    for (int i = 0; i < SUB; ++i) { soff[i] = a; a += scnt[i]; }
    soff[SUB] = a;
  }
  __syncthreads();
  int total = soff[SUB];

#pragma unroll
  for (int i = 0; i < SUB; ++i) {
    const int* ep = ents + (size_t)(b * SUB + i) * CAPS;
    for (int j = tid; j < scnt[i]; j += 256) stage[soff[i] + j] = ep[j];
  }
  __syncthreads();

  for (int j = tid; j < total; j += 256) atomicAdd(&hist[stage[j] & 63], 1);
  __syncthreads();

  if (tid < 64) {
    int c = hist[tid];
    int x = c;
#pragma unroll
    for (int off = 1; off < 64; off <<= 1) {
      int t = __shfl_up(x, off);
      if (tid >= off) x += t;
    }
    int excl = x - c;
    cur[tid] = excl;
    int r = b * 64 + tid;
    if (r < N) {
      start_[r] = base + excl;
      end_[r] = base + excl + c;
      dinv[r] = rsqrtf((float)(c + 1));
    }
  }
  __syncthreads();

  for (int j = tid; j < total; j += 256) {
    int e = stage[j];
    int p = atomicAdd(&cur[e & 63], 1);
    sorted[p] = e >> 6;
  }
  __syncthreads();

  for (int j = tid; j < total; j += 256) csr[base + j] = sorted[j];
}

// y1 = fp16((x @ W1) * dinv[row]). Register-tiled 64x64/block, 4x4 acc/thread.
__global__ __launch_bounds__(256) void gemm1_kernel(
    const float* __restrict__ x, const float* __restrict__ W1,
    const float* __restrict__ dinv, __half* __restrict__ y1, int N) {
  __shared__ float Xs[IN_DIM][68];
  __shared__ float Ws[IN_DIM * HID];

  for (int i = threadIdx.x; i < IN_DIM * HID / 4; i += 256)
    ((float4*)Ws)[i] = ((const float4*)W1)[i];

  int r0 = blockIdx.x * 64;
  {
    int row = threadIdx.x >> 2;
    int kc = (threadIdx.x & 3) * 32;
    int gr = r0 + row;
    const float* xp = x + (size_t)(gr < N ? gr : N - 1) * IN_DIM + kc;
#pragma unroll
    for (int i = 0; i < 8; ++i) {
      float4 v = *(const float4*)(xp + i * 4);
      int k = kc + i * 4;
      Xs[k + 0][row] = v.x;
      Xs[k + 1][row] = v.y;
      Xs[k + 2][row] = v.z;
      Xs[k + 3][row] = v.w;
    }
  }
  __syncthreads();

  int tr = (threadIdx.x & 15) * 4;
  int tc = (threadIdx.x >> 4) * 4;
  float acc[4][4];
#pragma unroll
  for (int i = 0; i < 4; ++i)
#pragma unroll
    for (int j = 0; j < 4; ++j) acc[i][j] = 0.f;

#pragma unroll 8
  for (int k = 0; k < IN_DIM; ++k) {
    float4 a = *(const float4*)&Xs[k][tr];
    float4 bb = *(const float4*)&Ws[k * HID + tc];
    acc[0][0] = fmaf(a.x, bb.x, acc[0][0]); acc[0][1] = fmaf(a.x, bb.y, acc[0][1]);
    acc[0][2] = fmaf(a.x, bb.z, acc[0][2]); acc[0][3] = fmaf(a.x, bb.w, acc[0][3]);
    acc[1][0] = fmaf(a.y, bb.x, acc[1][0]); acc[1][1] = fmaf(a.y, bb.y, acc[1][1]);
    acc[1][2] = fmaf(a.y, bb.z, acc[1][2]); acc[1][3] = fmaf(a.y, bb.w, acc[1][3]);
    acc[2][0] = fmaf(a.z, bb.x, acc[2][0]); acc[2][1] = fmaf(a.z, bb.y, acc[2][1]);
    acc[2][2] = fmaf(a.z, bb.z, acc[2][2]); acc[2][3] = fmaf(a.z, bb.w, acc[2][3]);
    acc[3][0] = fmaf(a.w, bb.x, acc[3][0]); acc[3][1] = fmaf(a.w, bb.y, acc[3][1]);
    acc[3][2] = fmaf(a.w, bb.z, acc[3][2]); acc[3][3] = fmaf(a.w, bb.w, acc[3][3]);
  }

#pragma unroll
  for (int i = 0; i < 4; ++i) {
    int r = r0 + tr + i;
    if (r < N) {
      float di = dinv[r];
      ushort4 w;
      w.x = __half_as_ushort(__float2half(acc[i][0] * di));
      w.y = __half_as_ushort(__float2half(acc[i][1] * di));
      w.z = __half_as_ushort(__float2half(acc[i][2] * di));
      w.w = __half_as_ushort(__float2half(acc[i][3] * di));
      *(ushort4*)(y1 + ((size_t)r << 6) + tc) = w;
    }
  }
}

// Non-temporal gather of one fp16 element at row s, column lane.
__device__ __forceinline__ float nt_gather(const __half* __restrict__ y,
                                           unsigned off) {
  return __half2float(__ushort_as_half(
      __builtin_nontemporal_load((const unsigned short*)y + off)));
}

// Sum up to m (<=64) neighbor rows of y at this lane's column. 16-deep ILP,
// non-temporal loads (no intra-CU reuse -> skip L1 retention).
#define GSTEP(U, A) { unsigned o = ((unsigned)__shfl(idx, i + U) << 6) | lane; \
                      A += nt_gather(y, o); }
__device__ __forceinline__ float gather_row(
    const __half* __restrict__ y, int idx, int m, unsigned lane) {
  float a0 = 0.f, a1 = 0.f, a2 = 0.f, a3 = 0.f;
  float a4 = 0.f, a5 = 0.f, a6 = 0.f, a7 = 0.f;
  float a8 = 0.f, a9 = 0.f, a10 = 0.f, a11 = 0.f;
  float a12 = 0.f, a13 = 0.f, a14 = 0.f, a15 = 0.f;
  int i = 0;
  for (; i + 15 < m; i += 16) {
    GSTEP(0, a0)  GSTEP(1, a1)  GSTEP(2, a2)  GSTEP(3, a3)
    GSTEP(4, a4)  GSTEP(5, a5)  GSTEP(6, a6)  GSTEP(7, a7)
    GSTEP(8, a8)  GSTEP(9, a9)  GSTEP(10, a10) GSTEP(11, a11)
    GSTEP(12, a12) GSTEP(13, a13) GSTEP(14, a14) GSTEP(15, a15)
  }
  if (i + 7 < m) {
    GSTEP(0, a0) GSTEP(1, a1) GSTEP(2, a2) GSTEP(3, a3)
    GSTEP(4, a4) GSTEP(5, a5) GSTEP(6, a6) GSTEP(7, a7)
    i += 8;
  }
  if (i + 3 < m) {
    GSTEP(0, a8) GSTEP(1, a9) GSTEP(2, a10) GSTEP(3, a11)
    i += 4;
  }
  for (; i < m; ++i) GSTEP(0, a12)
  return (((a0 + a1) + (a2 + a3)) + ((a4 + a5) + (a6 + a7))) +
         (((a8 + a9) + (a10 + a11)) + ((a12 + a13) + (a14 + a15)));
}
#undef GSTEP

// h[r] = relu((y1[r] + sum_in) * dinv[r] + b1); y2[r] = fp16((h[r]@W2)*dinv[r]).
__global__ __launch_bounds__(256) void agg1_gemm2_kernel(
    const __half* __restrict__ y1, const int* __restrict__ start_,
    const int* __restrict__ end_, const int* __restrict__ csr,
    const float* __restrict__ dinv, const float* __restrict__ b1,
    const float* __restrict__ W2, __half* __restrict__ y2, int N) {
  __shared__ float Ws[HID * HID];
  __shared__ float hs[4][HID];
  for (int i = threadIdx.x; i < HID * HID / 4; i += 256)
    ((float4*)Ws)[i] = ((const float4*)W2)[i];
  __syncthreads();  // only barrier; waves decoupled after this

  int wave = threadIdx.x >> 6;
  unsigned lane = threadIdx.x & 63;
  int r = blockIdx.x * 4 + wave;
  bool valid = r < N;
  int rr = valid ? r : N - 1;

  int jb = start_[rr], je = end_[rr];
  int cnt = je - jb;
  int m = cnt < 64 ? cnt : 64;
  int idx = ((int)lane < cnt) ? csr[jb + lane] : 0;

  float acc = __half2float(y1[((unsigned)rr << 6) | lane]);  // self loop
  acc += gather_row(y1, idx, m, lane);
  for (int j = jb + 64; j < je; ++j)  // deg>64 tail (rare)
    acc += nt_gather(y1, ((unsigned)csr[j] << 6) | lane);

  float di = dinv[rr];
  hs[wave][lane] = fmaxf(fmaf(acc, di, b1[lane]), 0.f);
  // same-wave LDS dep: lockstep wave + compiler lgkmcnt wait; no barrier.

  float c0 = 0.f, c1 = 0.f, c2 = 0.f, c3 = 0.f;
#pragma unroll
  for (int k = 0; k < HID; k += 4) {
    float4 hv = *(const float4*)&hs[wave][k];
    c0 = fmaf(hv.x, Ws[(k + 0) * HID + lane], c0);
    c1 = fmaf(hv.y, Ws[(k + 1) * HID + lane], c1);
    c2 = fmaf(hv.z, Ws[(k + 2) * HID + lane], c2);
    c3 = fmaf(hv.w, Ws[(k + 3) * HID + lane], c3);
  }
  if (valid)
    y2[((unsigned)r << 6) | lane] = __float2half(((c0 + c1) + (c2 + c3)) * di);
}

// out[r] = (y2[r] + sum_in) * dinv[r] + b2. f32 output.
__global__ __launch_bounds__(256) void agg2_kernel(
    const __half* __restrict__ y2, const int* __restrict__ start_,
    const int* __restrict__ end_, const int* __restrict__ csr,
    const float* __restrict__ dinv, const float* __restrict__ b2,
    float* __restrict__ out, int N) {
  int wave = threadIdx.x >> 6;
  unsigned lane = threadIdx.x & 63;
  int r = blockIdx.x * 4 + wave;
  if (r >= N) return;

  int jb = start_[r], je = end_[r];
  int cnt = je - jb;
  int m = cnt < 64 ? cnt : 64;
  int idx = ((int)lane < cnt) ? csr[jb + lane] : 0;

  float acc = __half2float(y2[((unsigned)r << 6) | lane]);  // self loop
  acc += gather_row(y2, idx, m, lane);
  for (int j = jb + 64; j < je; ++j)
    acc += nt_gather(y2, ((unsigned)csr[j] << 6) | lane);

  out[((unsigned)r << 6) | lane] = fmaf(acc, dinv[r], b2[lane]);
}

extern "C" void kernel_launch(void* const* d_in, const int* in_sizes, int n_in,
                              void* d_out, int out_size, void* d_ws, size_t ws_size,
                              hipStream_t stream) {
  const float* x   = (const float*)d_in[0];
  const int* edges = (const int*)d_in[1];
  const float* W1  = (const float*)d_in[2];
  const float* b1  = (const float*)d_in[3];
  const float* W2  = (const float*)d_in[4];
  const float* b2  = (const float*)d_in[5];
  float* out = (float*)d_out;

  const int N = in_sizes[0] / IN_DIM;   // 100000
  const int E = in_sizes[1] / 2;        // 1600000
  const int* src = edges;
  const int* dst = edges + E;
  const int NBUCK = (N + 63) / 64;      // 1563

  char* wsb = (char*)d_ws;
  float*  dinv   = (float*)(wsb + 0);
  int*    start_ = (int*)(wsb + (size_t)512 * 1024);
  int*    end_   = (int*)(wsb + (size_t)1024 * 1024);
  int*    bcur   = (int*)(wsb + (size_t)1536 * 1024);
  int*    ents   = (int*)(wsb + (size_t)3 * 1024 * 1024);
  int*    csr    = ents;  // in-place (LDS-staged sort)
  __half* y1     = (__half*)(wsb + (size_t)16 * 1024 * 1024);  // 12.8MB
  __half* y2     = (__half*)(wsb + (size_t)30 * 1024 * 1024);  // 12.8MB

  const int blk = 256;
  int gE = (E + blk - 1) / blk;
  int gG = (N + 63) / 64;
  int gR = (N + 3) / 4;

  hipMemsetAsync(bcur, 0, (size_t)NBUCK * SUB * CURPAD * 4, stream);
  fill_kernel<<<gE, blk, 0, stream>>>(src, dst, bcur, ents, E);
  sort_kernel<<<NBUCK, blk, 0, stream>>>(ents, bcur, csr, start_, end_, dinv, N);

  gemm1_kernel<<<gG, blk, 0, stream>>>(x, W1, dinv, y1, N);
  agg1_gemm2_kernel<<<gR, blk, 0, stream>>>(y1, start_, end_, csr, dinv, b1, W2, y2, N);
  agg2_kernel<<<gR, blk, 0, stream>>>(y2, start_, end_, csr, dinv, b2, out, N);
}

// Round 15
// 260.827 us; speedup vs baseline: 5.6338x; 1.1828x over previous
//
#include <hip/hip_runtime.h>
#include <hip/hip_bf16.h>
#include <hip/hip_fp16.h>

// 2-layer GCN (PyG GCNConv) on MI355X. N=100000, E=1.6M, IN=128, HID=OUT=64.
//
// Algebra: y = (x@W) * dinv[row]; agg[d] = y[d] + sum_{e:(s->d)} y[s];
//          out[d] = agg[d]*dinv[d] + b  (self-loop folded into agg init).
//
// FINAL (= R12, best measured 261 us). CSR via bucketed fill (XCD-affine
// sub-segments) + per-bucket LDS counting sort (256 bins, in-place).
// Aggregation: one wave per row, 16-deep gather ILP, 32-bit offsets,
// plain (cached) gather loads. y1/y2 fp16 storage, f32 accumulation.
//
// Session evidence for this being the gather-service roofline:
//   bytes/edge halved (fp16)      -> -3% time   (R8)
//   16-deep nominal ILP           -> null       (R10)
//   2 rows/wave, 32 loads in-flight -> -6%      (R11)
//   src-chunk-sorted rows         -> null       (R12)
//   paired-edge half2 (2 seg/instr) -> +20%     (R9)
//   LDS-tile privatization        -> 5x worse   (R4, R13)
//   non-temporal loads            -> +23%       (R14)
// Invariant: 1.6M single-row random gathers/layer @ ~42 CU-cyc each.

#define IN_DIM 128
#define HID 64
#define SUB 8
#define CAPS 256
#define CURPAD 16
#define BENT (SUB * CAPS)

__global__ __launch_bounds__(256) void fill_kernel(
    const int* __restrict__ src, const int* __restrict__ dst,
    int* __restrict__ bcur, int* __restrict__ ents, int E) {
  int e = blockIdx.x * 256 + threadIdx.x;
  if (e >= E) return;
  int s = src[e], d = dst[e];
  int seg = (d >> 6) * SUB + (blockIdx.x & 7);
  int pos = atomicAdd(&bcur[seg * CURPAD], 1);
  if (pos < CAPS) ents[(size_t)seg * CAPS + pos] = (s << 6) | (d & 63);
}

// Per bucket: counting-sort by 256-bin key ((dst&63)<<2)|(src>>15).
__global__ __launch_bounds__(256) void sort_kernel(
    const int* __restrict__ ents, const int* __restrict__ bcur,
    int* __restrict__ csr, int* __restrict__ start4, int* __restrict__ end_,
    float* __restrict__ dinv, int N) {
  __shared__ int stage[BENT];
  __shared__ int sorted[BENT];
  __shared__ int scnt[SUB], soff[SUB + 1];
  __shared__ int hist[256], cur[256];
  __shared__ int wsum[4];
  int b = blockIdx.x, tid = threadIdx.x;
  int wave = tid >> 6, lane = tid & 63;
  int base = b * BENT;

  if (tid < SUB) {
    int c = bcur[(b * SUB + tid) * CURPAD];
    scnt[tid] = c < CAPS ? c : CAPS;
  }
  hist[tid] = 0;
  __syncthreads();
  if (tid == 0) {
    int a = 0;
#pragma unroll
    for (int i = 0; i < SUB; ++i) { soff[i] = a; a += scnt[i]; }
    soff[SUB] = a;
  }
  __syncthreads();
  int total = soff[SUB];

#pragma unroll
  for (int i = 0; i < SUB; ++i) {
    const int* ep = ents + (size_t)(b * SUB + i) * CAPS;
    for (int j = tid; j < scnt[i]; j += 256) stage[soff[i] + j] = ep[j];
  }
  __syncthreads();

  for (int j = tid; j < total; j += 256)
    atomicAdd(&hist[((stage[j] & 63) << 2) | ((unsigned)stage[j] >> 21)], 1);
  __syncthreads();

  int c = hist[tid];
  int x = c;
#pragma unroll
  for (int off = 1; off < 64; off <<= 1) {
    int t = __shfl_up(x, off);
    if (lane >= off) x += t;
  }
  if (lane == 63) wsum[wave] = x;
  __syncthreads();
  int wo = 0;
#pragma unroll
  for (int i = 0; i < 4; ++i) wo += (i < wave) ? wsum[i] : 0;
  int excl = wo + x - c;
  cur[tid] = excl;
  start4[b * 256 + tid] = base + excl;
  __syncthreads();

  if (tid < 64) {
    int tot = wsum[0] + wsum[1] + wsum[2] + wsum[3];
    int r = b * 64 + tid;
    int s0 = cur[tid * 4];
    int e0 = (tid == 63) ? tot : cur[tid * 4 + 4];
    if (r < N) {
      end_[r] = base + e0;
      dinv[r] = rsqrtf((float)(e0 - s0 + 1));  // +1 self loop
    }
  }
  __syncthreads();

  for (int j = tid; j < total; j += 256) {
    int e = stage[j];
    int p = atomicAdd(&cur[((e & 63) << 2) | ((unsigned)e >> 21)], 1);
    sorted[p] = e >> 6;
  }
  __syncthreads();

  for (int j = tid; j < total; j += 256) csr[base + j] = sorted[j];
}

// y1 = fp16((x @ W1) * dinv[row]). Register-tiled 64x64/block, 4x4 acc/thread.
__global__ __launch_bounds__(256) void gemm1_kernel(
    const float* __restrict__ x, const float* __restrict__ W1,
    const float* __restrict__ dinv, __half* __restrict__ y1, int N) {
  __shared__ float Xs[IN_DIM][68];
  __shared__ float Ws[IN_DIM * HID];

  for (int i = threadIdx.x; i < IN_DIM * HID / 4; i += 256)
    ((float4*)Ws)[i] = ((const float4*)W1)[i];

  int r0 = blockIdx.x * 64;
  {
    int row = threadIdx.x >> 2;
    int kc = (threadIdx.x & 3) * 32;
    int gr = r0 + row;
    const float* xp = x + (size_t)(gr < N ? gr : N - 1) * IN_DIM + kc;
#pragma unroll
    for (int i = 0; i < 8; ++i) {
      float4 v = *(const float4*)(xp + i * 4);
      int k = kc + i * 4;
      Xs[k + 0][row] = v.x;
      Xs[k + 1][row] = v.y;
      Xs[k + 2][row] = v.z;
      Xs[k + 3][row] = v.w;
    }
  }
  __syncthreads();

  int tr = (threadIdx.x & 15) * 4;
  int tc = (threadIdx.x >> 4) * 4;
  float acc[4][4];
#pragma unroll
  for (int i = 0; i < 4; ++i)
#pragma unroll
    for (int j = 0; j < 4; ++j) acc[i][j] = 0.f;

#pragma unroll 8
  for (int k = 0; k < IN_DIM; ++k) {
    float4 a = *(const float4*)&Xs[k][tr];
    float4 bb = *(const float4*)&Ws[k * HID + tc];
    acc[0][0] = fmaf(a.x, bb.x, acc[0][0]); acc[0][1] = fmaf(a.x, bb.y, acc[0][1]);
    acc[0][2] = fmaf(a.x, bb.z, acc[0][2]); acc[0][3] = fmaf(a.x, bb.w, acc[0][3]);
    acc[1][0] = fmaf(a.y, bb.x, acc[1][0]); acc[1][1] = fmaf(a.y, bb.y, acc[1][1]);
    acc[1][2] = fmaf(a.y, bb.z, acc[1][2]); acc[1][3] = fmaf(a.y, bb.w, acc[1][3]);
    acc[2][0] = fmaf(a.z, bb.x, acc[2][0]); acc[2][1] = fmaf(a.z, bb.y, acc[2][1]);
    acc[2][2] = fmaf(a.z, bb.z, acc[2][2]); acc[2][3] = fmaf(a.z, bb.w, acc[2][3]);
    acc[3][0] = fmaf(a.w, bb.x, acc[3][0]); acc[3][1] = fmaf(a.w, bb.y, acc[3][1]);
    acc[3][2] = fmaf(a.w, bb.z, acc[3][2]); acc[3][3] = fmaf(a.w, bb.w, acc[3][3]);
  }

#pragma unroll
  for (int i = 0; i < 4; ++i) {
    int r = r0 + tr + i;
    if (r < N) {
      float di = dinv[r];
      ushort4 w;
      w.x = __half_as_ushort(__float2half(acc[i][0] * di));
      w.y = __half_as_ushort(__float2half(acc[i][1] * di));
      w.z = __half_as_ushort(__float2half(acc[i][2] * di));
      w.w = __half_as_ushort(__float2half(acc[i][3] * di));
      *(ushort4*)(y1 + ((size_t)r << 6) + tc) = w;
    }
  }
}

// Sum up to m (<=64) neighbor rows of y at this lane's column. 16-deep ILP.
#define GSTEP(U, A) { unsigned o = ((unsigned)__shfl(idx, i + U) << 6) | lane; \
                      A += __half2float(y[o]); }
__device__ __forceinline__ float gather_row(
    const __half* __restrict__ y, int idx, int m, unsigned lane) {
  float a0 = 0.f, a1 = 0.f, a2 = 0.f, a3 = 0.f;
  float a4 = 0.f, a5 = 0.f, a6 = 0.f, a7 = 0.f;
  float a8 = 0.f, a9 = 0.f, a10 = 0.f, a11 = 0.f;
  float a12 = 0.f, a13 = 0.f, a14 = 0.f, a15 = 0.f;
  int i = 0;
  for (; i + 15 < m; i += 16) {
    GSTEP(0, a0)  GSTEP(1, a1)  GSTEP(2, a2)  GSTEP(3, a3)
    GSTEP(4, a4)  GSTEP(5, a5)  GSTEP(6, a6)  GSTEP(7, a7)
    GSTEP(8, a8)  GSTEP(9, a9)  GSTEP(10, a10) GSTEP(11, a11)
    GSTEP(12, a12) GSTEP(13, a13) GSTEP(14, a14) GSTEP(15, a15)
  }
  if (i + 7 < m) {
    GSTEP(0, a0) GSTEP(1, a1) GSTEP(2, a2) GSTEP(3, a3)
    GSTEP(4, a4) GSTEP(5, a5) GSTEP(6, a6) GSTEP(7, a7)
    i += 8;
  }
  if (i + 3 < m) {
    GSTEP(0, a8) GSTEP(1, a9) GSTEP(2, a10) GSTEP(3, a11)
    i += 4;
  }
  for (; i < m; ++i) GSTEP(0, a12)
  return (((a0 + a1) + (a2 + a3)) + ((a4 + a5) + (a6 + a7))) +
         (((a8 + a9) + (a10 + a11)) + ((a12 + a13) + (a14 + a15)));
}
#undef GSTEP

// h[r] = relu((y1[r] + sum_in) * dinv[r] + b1); y2[r] = fp16((h[r]@W2)*dinv[r]).
__global__ __launch_bounds__(256) void agg1_gemm2_kernel(
    const __half* __restrict__ y1, const int* __restrict__ start4,
    const int* __restrict__ end_, const int* __restrict__ csr,
    const float* __restrict__ dinv, const float* __restrict__ b1,
    const float* __restrict__ W2, __half* __restrict__ y2, int N) {
  __shared__ float Ws[HID * HID];
  __shared__ float hs[4][HID];
  for (int i = threadIdx.x; i < HID * HID / 4; i += 256)
    ((float4*)Ws)[i] = ((const float4*)W2)[i];
  __syncthreads();  // only barrier; waves decoupled after this

  int wave = threadIdx.x >> 6;
  unsigned lane = threadIdx.x & 63;
  int r = blockIdx.x * 4 + wave;
  bool valid = r < N;
  int rr = valid ? r : N - 1;

  int jb = start4[rr << 2], je = end_[rr];
  int cnt = je - jb;
  int m = cnt < 64 ? cnt : 64;
  int idx = ((int)lane < cnt) ? csr[jb + lane] : 0;

  float acc = __half2float(y1[((unsigned)rr << 6) | lane]);  // self loop
  acc += gather_row(y1, idx, m, lane);
  for (int j = jb + 64; j < je; ++j)  // deg>64 tail (rare)
    acc += __half2float(y1[((unsigned)csr[j] << 6) | lane]);

  float di = dinv[rr];
  hs[wave][lane] = fmaxf(fmaf(acc, di, b1[lane]), 0.f);
  // same-wave LDS dep: lockstep wave + compiler lgkmcnt wait; no barrier.

  float c0 = 0.f, c1 = 0.f, c2 = 0.f, c3 = 0.f;
#pragma unroll
  for (int k = 0; k < HID; k += 4) {
    float4 hv = *(const float4*)&hs[wave][k];
    c0 = fmaf(hv.x, Ws[(k + 0) * HID + lane], c0);
    c1 = fmaf(hv.y, Ws[(k + 1) * HID + lane], c1);
    c2 = fmaf(hv.z, Ws[(k + 2) * HID + lane], c2);
    c3 = fmaf(hv.w, Ws[(k + 3) * HID + lane], c3);
  }
  if (valid)
    y2[((unsigned)r << 6) | lane] = __float2half(((c0 + c1) + (c2 + c3)) * di);
}

// out[r] = (y2[r] + sum_in) * dinv[r] + b2. f32 output.
__global__ __launch_bounds__(256) void agg2_kernel(
    const __half* __restrict__ y2, const int* __restrict__ start4,
    const int* __restrict__ end_, const int* __restrict__ csr,
    const float* __restrict__ dinv, const float* __restrict__ b2,
    float* __restrict__ out, int N) {
  int wave = threadIdx.x >> 6;
  unsigned lane = threadIdx.x & 63;
  int r = blockIdx.x * 4 + wave;
  if (r >= N) return;

  int jb = start4[r << 2], je = end_[r];
  int cnt = je - jb;
  int m = cnt < 64 ? cnt : 64;
  int idx = ((int)lane < cnt) ? csr[jb + lane] : 0;

  float acc = __half2float(y2[((unsigned)r << 6) | lane]);  // self loop
  acc += gather_row(y2, idx, m, lane);
  for (int j = jb + 64; j < je; ++j)
    acc += __half2float(y2[((unsigned)csr[j] << 6) | lane]);

  out[((unsigned)r << 6) | lane] = fmaf(acc, dinv[r], b2[lane]);
}

extern "C" void kernel_launch(void* const* d_in, const int* in_sizes, int n_in,
                              void* d_out, int out_size, void* d_ws, size_t ws_size,
                              hipStream_t stream) {
  const float* x   = (const float*)d_in[0];
  const int* edges = (const int*)d_in[1];
  const float* W1  = (const float*)d_in[2];
  const float* b1  = (const float*)d_in[3];
  const float* W2  = (const float*)d_in[4];
  const float* b2  = (const float*)d_in[5];
  float* out = (float*)d_out;

  const int N = in_sizes[0] / IN_DIM;   // 100000
  const int E = in_sizes[1] / 2;        // 1600000
  const int* src = edges;
  const int* dst = edges + E;
  const int NBUCK = (N + 63) / 64;      // 1563

  char* wsb = (char*)d_ws;
  float*  dinv   = (float*)(wsb + 0);                        // 400KB
  int*    end_   = (int*)(wsb + (size_t)512 * 1024);         // 400KB
  int*    bcur   = (int*)(wsb + (size_t)1024 * 1024);        // 0.77MB
  int*    start4 = (int*)(wsb + (size_t)2 * 1024 * 1024);    // 1.6MB
  int*    ents   = (int*)(wsb + (size_t)4 * 1024 * 1024);    // 12.8MB
  int*    csr    = ents;  // in-place (LDS-staged sort)
  __half* y1     = (__half*)(wsb + (size_t)17 * 1024 * 1024); // 12.8MB
  __half* y2     = (__half*)(wsb + (size_t)30 * 1024 * 1024); // 12.8MB

  const int blk = 256;
  int gE = (E + blk - 1) / blk;
  int gG = (N + 63) / 64;
  int gR = (N + 3) / 4;

  hipMemsetAsync(bcur, 0, (size_t)NBUCK * SUB * CURPAD * 4, stream);
  fill_kernel<<<gE, blk, 0, stream>>>(src, dst, bcur, ents, E);
  sort_kernel<<<NBUCK, blk, 0, stream>>>(ents, bcur, csr, start4, end_, dinv, N);

  gemm1_kernel<<<gG, blk, 0, stream>>>(x, W1, dinv, y1, N);
  agg1_gemm2_kernel<<<gR, blk, 0, stream>>>(y1, start4, end_, csr, dinv, b1, W2, y2, N);
  agg2_kernel<<<gR, blk, 0, stream>>>(y2, start4, end_, csr, dinv, b2, out, N);
}